// Round 5
// baseline (378.507 us; speedup 1.0000x reference)
//
#include <hip/hip_runtime.h>

// Problem constants
#define B_Q   4096
#define E_DIM 512
#define N_C   2000
#define N_P   64000

// 256x256 tile, BK=64 (2 k-halves of 32), 8 waves (2M x 4N), 8-phase schedule,
// double-buffered 128 KiB LDS.  Persistent blocks, ROW-sweep: 256 blocks; each
// fixes one B column tile (colb) and streams 15-16 A panels (rowb = g + 16*i)
// with the staging pipeline CONTINUOUS across panel boundaries.  The 16 blocks
// sharing g (same A panels) are co-located on one XCD (g = xcd*2 + slot/16) so
// each A panel is fetched ~once from HBM and hits L2 for the siblings.
#define BM 256
#define BN 256

typedef __bf16 bf16x8 __attribute__((ext_vector_type(8)));
typedef float  f32x4  __attribute__((ext_vector_type(4)));

__device__ __forceinline__ unsigned short f2bf(float f) {
  unsigned u = __builtin_bit_cast(unsigned, f);
  u += 0x7fffu + ((u >> 16) & 1u);
  return (unsigned short)(u >> 16);
}

__device__ __forceinline__ void async_ld16(const void* g, void* l) {
  __builtin_amdgcn_global_load_lds(
      (const __attribute__((address_space(1))) void*)g,
      (__attribute__((address_space(3))) void*)l,
      16, 0, 0);
}

// ---------------------------------------------------------------------------
// Row L2-normalize fp32 -> bf16.  One block (128 threads) per 512-elem row.
// ---------------------------------------------------------------------------
__global__ __launch_bounds__(128) void norm_rows_kernel(
    const float* __restrict__ in, unsigned short* __restrict__ outbf)
{
  const int row = blockIdx.x;
  const int tid = threadIdx.x;
  const float4 v = *(const float4*)(in + (size_t)row * E_DIM + tid * 4);
  float ss = v.x*v.x + v.y*v.y + v.z*v.z + v.w*v.w;
  #pragma unroll
  for (int s = 1; s < 64; s <<= 1) ss += __shfl_xor(ss, s);
  __shared__ float partial[2];
  if ((tid & 63) == 0) partial[tid >> 6] = ss;
  __syncthreads();
  const float tot = partial[0] + partial[1];
  const float inv = 1.0f / fmaxf(sqrtf(tot), 1e-12f);
  ushort4 o;
  o.x = f2bf(v.x * inv); o.y = f2bf(v.y * inv);
  o.z = f2bf(v.z * inv); o.w = f2bf(v.w * inv);
  *(ushort4*)(outbf + (size_t)row * E_DIM + tid * 4) = o;
}

// ---------------------------------------------------------------------------
// LDS: A[buf][h][256 rows][4 x 16B] @0, B same @65536; region = 16 KiB.
// Chunk swizzle: slot (row,cc) holds global chunk cc ^ ((row>>1)&3); stager
// pre-swizzles the GLOBAL source chunk, LDS dest stays linear.
// Ledger per ii-block (computes k-tile g from buf0 ph1-4, g+1 from buf1 ph5-8):
//   p1 A(1,1,g+1)  p2 B(1,1,g+1)  p3 A(0,0,g+2)  p4 B(0,0,g+2)
//   p5 A(0,1,g+2)  p6 B(0,1,g+2)  p7 A(1,0,g+3)  p8 B(1,0,g+3)
// vmcnt(8) after even-phase stage guarantees the region needed two phases
// later has landed.  Per-tile epilogue stores add vmcnt entries; the next
// WAITV(8) just waits longer (safe, once/tile).  B is restaged each tile from
// the same (L2-hot) column addresses -- required by the buf rotation.
// ---------------------------------------------------------------------------
#define WAITV(N) asm volatile("s_waitcnt vmcnt(" #N ")" ::: "memory")
#define SBAR     asm volatile("s_barrier" ::: "memory")
#define NOPS     do {} while (0)

#define STAGE_A(BUF,H,PTR,KOFF) do { \
  async_ld16((PTR) + (KOFF)*64 + (H)*32,         smem + (BUF)*32768 + (H)*16384 + sdst); \
  async_ld16((PTR) + 65536 + (KOFF)*64 + (H)*32, smem + (BUF)*32768 + (H)*16384 + sdst + 8192); \
} while(0)

#define STAGE_B(BUF,H,KOFF) do { \
  async_ld16(gB + (KOFF)*64 + (H)*32,         smem + 65536 + (BUF)*32768 + (H)*16384 + sdst); \
  async_ld16(gB + 65536 + (KOFF)*64 + (H)*32, smem + 65536 + (BUF)*32768 + (H)*16384 + sdst + 8192); \
} while(0)

#define PH(BUF,H,MH,RB, STAGE, WAIT) do { \
  if (RB) { \
    _Pragma("unroll") \
    for (int n = 0; n < 4; ++n) \
      bfr[n] = *(const bf16x8*)(pb + (BUF)*32768 + (H)*16384 + n*1024); \
  } \
  _Pragma("unroll") \
  for (int m = 0; m < 4; ++m) \
    afr[m] = *(const bf16x8*)(pa + (BUF)*32768 + (H)*16384 + ((MH)*4+m)*1024); \
  STAGE; \
  WAIT; \
  SBAR; \
  asm volatile("s_waitcnt lgkmcnt(0)" ::: "memory"); \
  __builtin_amdgcn_sched_barrier(0); \
  __builtin_amdgcn_s_setprio(1); \
  _Pragma("unroll") \
  for (int m = 0; m < 4; ++m) { \
    _Pragma("unroll") \
    for (int n = 0; n < 4; ++n) \
      acc[(MH)*4+m][n] = __builtin_amdgcn_mfma_f32_16x16x32_bf16( \
          afr[m], bfr[n], acc[(MH)*4+m][n], 0, 0, 0); \
  } \
  __builtin_amdgcn_s_setprio(0); \
  SBAR; \
} while(0)

// One ii-block: k-tiles g (buf0), g+1 (buf1); A gets the wrap pointer PA23
// for k-tiles g+2, g+3 (may belong to the next A panel), B column is fixed.
#define IIBLK(K1,K2,K3, PA23) do { \
  PH(0,0,0,1, STAGE_A(1,1,gA,K1),   NOPS); \
  PH(0,0,1,0, STAGE_B(1,1,K1),      WAITV(8)); \
  PH(0,1,0,1, STAGE_A(0,0,PA23,K2), NOPS); \
  PH(0,1,1,0, STAGE_B(0,0,K2),      WAITV(8)); \
  PH(1,0,0,1, STAGE_A(0,1,PA23,K2), NOPS); \
  PH(1,0,1,0, STAGE_B(0,1,K2),      WAITV(8)); \
  PH(1,1,0,1, STAGE_A(1,0,PA23,K3), NOPS); \
  PH(1,1,1,0, STAGE_B(1,0,K3),      WAITV(8)); \
} while(0)

#define EPILOGUE do { \
  _Pragma("unroll") \
  for (int q = 0; q < 4; ++q) { \
    _Pragma("unroll") \
    for (int n = 0; n < 4; ++n) { \
      float pm = -3.4e38f; \
      _Pragma("unroll") \
      for (int j = 0; j < 4; ++j) \
        pm = fmaxf(pm, fmaxf(acc[2*q][n][j], acc[2*q+1][n][j])); \
      pm = fmaxf(pm, __shfl_xor(pm, 16)); \
      pm = fmaxf(pm, __shfl_xor(pm, 32)); \
      if (lane < 16) outp[q * B_Q + n * 16] = pm; \
    } \
  } \
} while(0)

__global__ __launch_bounds__(512, 2) void gemm_max_kernel(
    const unsigned short* __restrict__ wbf,   // [64000][512] bf16, normalized
    const unsigned short* __restrict__ dbf,   // [4096][512]  bf16, normalized
    float* __restrict__ out)                  // [2000][4096]
{
  extern __shared__ char smem[];              // 131072 B

  const int tid  = threadIdx.x;
  const int lane = tid & 63;
  const int wid  = tid >> 6;      // 0..7
  const int wr   = wid >> 2;      // 0..1  (128 rows each)
  const int wc   = wid & 3;       // 0..3  (64 cols each)

  // Block -> (g, colb): the 16 blocks with equal g share every A panel and
  // sit on one XCD (hw round-robins blockIdx%8 across XCDs).
  const int xcd  = blockIdx.x & 7;
  const int slot = blockIdx.x >> 3;        // 0..31
  const int g    = xcd * 2 + (slot >> 4);  // 0..15
  const int colb = slot & 15;              // 0..15
  const int ntiles = (g < 10) ? 16 : 15;   // rowb = g + 16*i <= 249

  // Staging: region = 256 rows x 32 shorts = 1024 x 16B chunks; thread t
  // handles chunks t (rows 0-127) and t+512 (rows 128-255).
  const int srow = tid >> 2;
  const int gch  = (tid & 3) ^ ((tid >> 3) & 3);   // pre-swizzled global chunk
  const unsigned short* gA  = wbf + (size_t)(g * 256 + srow) * E_DIM + gch * 8;
  const unsigned short* gAn = gA + (size_t)16 * 256 * E_DIM;  // next panel
  const unsigned short* gB  = dbf + (size_t)(colb * 256 + srow) * E_DIM + gch * 8;
  const int sdst = tid * 16;      // linear LDS dest

  // Fragment read bases (swizzled chunk)
  const int r   = lane & 15;
  const int kg  = lane >> 4;
  const int swz = (kg ^ ((r >> 1) & 3)) * 16;
  const char* pa = smem + (wr * 128 + r) * 64 + swz;
  const char* pb = smem + 65536 + (wc * 64 + r) * 64 + swz;

  float* outp = out + (size_t)(g * 8 + wr * 4) * B_Q + colb * BN + wc * 64 + r;

  f32x4 acc[8][4];
  #pragma unroll
  for (int m = 0; m < 8; ++m)
    #pragma unroll
    for (int n = 0; n < 4; ++n)
      acc[m][n] = (f32x4){0.f, 0.f, 0.f, 0.f};
  bf16x8 afr[4], bfr[4];

  // Prologue: 12 loads (regions 0.h0, 0.h1, 1.h0), oldest 4 needed first.
  STAGE_A(0,0,gA,0); STAGE_B(0,0,0);
  STAGE_A(0,1,gA,0); STAGE_B(0,1,0);
  STAGE_A(1,0,gA,1); STAGE_B(1,0,1);
  WAITV(8);
  SBAR;

  #pragma unroll 1
  for (int it = 0; it < ntiles - 1; ++it) {
    IIBLK(1,2,3, gA);
    IIBLK(3,4,5, gA);
    IIBLK(5,6,7, gA);
    IIBLK(7,0,1, gAn);           // k+2,k+3 wrap into next A panel's tiles 0,1
    EPILOGUE;
    #pragma unroll
    for (int m = 0; m < 8; ++m)
      #pragma unroll
      for (int n = 0; n < 4; ++n)
        acc[m][n] = (f32x4){0.f, 0.f, 0.f, 0.f};
    gA = gAn; gAn += (size_t)16 * 256 * E_DIM;
    outp += (size_t)128 * B_Q;   // 16 rowb * 8 classes
  }

  // Tail panel: 3 normal ii-blocks + drain block.
  IIBLK(1,2,3, gA);
  IIBLK(3,4,5, gA);
  IIBLK(5,6,7, gA);
  PH(0,0,0,1, STAGE_A(1,1,gA,7), NOPS);
  PH(0,0,1,0, STAGE_B(1,1,7),    WAITV(8));
  PH(0,1,0,1, NOPS,              NOPS);
  PH(0,1,1,0, NOPS,              WAITV(4));
  PH(1,0,0,1, NOPS,              NOPS);
  PH(1,0,1,0, NOPS,              WAITV(0));
  PH(1,1,0,1, NOPS,              NOPS);
  PH(1,1,1,0, NOPS,              NOPS);
  EPILOGUE;
}

// ---------------------------------------------------------------------------
extern "C" void kernel_launch(void* const* d_in, const int* in_sizes, int n_in,
                              void* d_out, int out_size, void* d_ws, size_t ws_size,
                              hipStream_t stream) {
  const float* data = (const float*)d_in[0];   // [4096][512]
  const float* w1   = (const float*)d_in[1];   // [64000][512]
  float* out = (float*)d_out;                  // [2000][4096]

  unsigned short* wbf = (unsigned short*)d_ws;
  unsigned short* dbf = wbf + (size_t)N_P * E_DIM;

  (void)hipFuncSetAttribute((const void*)gemm_max_kernel,
      hipFuncAttributeMaxDynamicSharedMemorySize, 131072);

  norm_rows_kernel<<<N_P, 128, 0, stream>>>(w1, wbf);
  norm_rows_kernel<<<B_Q, 128, 0, stream>>>(data, dbf);
  gemm_max_kernel<<<256, 512, 131072, stream>>>(wbf, dbf, out);
}

// Round 6
// 293.416 us; speedup vs baseline: 1.2900x; 1.2900x over previous
//
#include <hip/hip_runtime.h>

// Problem constants
#define B_Q   4096
#define E_DIM 512
#define N_C   2000
#define N_P   64000

// GEMM geometry: 256x256 tile, BK=64 (2 K-halves of 32), 8 waves (2M x 4N),
// 8-phase schedule, double-buffered 128 KiB LDS, 32x32x16 MFMA.
#define BM 256
#define BN 256

typedef __bf16 bf16x8 __attribute__((ext_vector_type(8)));
typedef float  f32x16 __attribute__((ext_vector_type(16)));

__device__ __forceinline__ unsigned short f2bf(float f) {
  unsigned u = __builtin_bit_cast(unsigned, f);
  u += 0x7fffu + ((u >> 16) & 1u);
  return (unsigned short)(u >> 16);
}

__device__ __forceinline__ void async_ld16(const void* g, void* l) {
  __builtin_amdgcn_global_load_lds(
      (const __attribute__((address_space(1))) void*)g,
      (__attribute__((address_space(3))) void*)l,
      16, 0, 0);
}

// ---------------------------------------------------------------------------
// Row L2-normalize fp32 -> bf16 for BOTH inputs in one launch.
// Blocks [0,64000) -> w1 rows; [64000,68096) -> data rows.
// ---------------------------------------------------------------------------
__global__ __launch_bounds__(128) void norm_rows_kernel(
    const float* __restrict__ w1, const float* __restrict__ data,
    unsigned short* __restrict__ wbf, unsigned short* __restrict__ dbf)
{
  int row = blockIdx.x;
  const float* in;
  unsigned short* outbf;
  if (row < N_P) { in = w1; outbf = wbf; }
  else           { in = data; outbf = dbf; row -= N_P; }
  const int tid = threadIdx.x;
  const float4 v = *(const float4*)(in + (size_t)row * E_DIM + tid * 4);
  float ss = v.x*v.x + v.y*v.y + v.z*v.z + v.w*v.w;
  #pragma unroll
  for (int s = 1; s < 64; s <<= 1) ss += __shfl_xor(ss, s);
  __shared__ float partial[2];
  if ((tid & 63) == 0) partial[tid >> 6] = ss;
  __syncthreads();
  const float tot = partial[0] + partial[1];
  const float inv = 1.0f / fmaxf(sqrtf(tot), 1e-12f);
  ushort4 o;
  o.x = f2bf(v.x * inv); o.y = f2bf(v.y * inv);
  o.z = f2bf(v.z * inv); o.w = f2bf(v.w * inv);
  *(ushort4*)(outbf + (size_t)row * E_DIM + tid * 4) = o;
}

// ---------------------------------------------------------------------------
// LDS: A[buf][h][256 rows][4 x 16B] @0, B same @65536; region = 16 KiB.
// Chunk swizzle: slot (row,cc) holds global chunk cc ^ ((row>>1)&3); stager
// pre-swizzles the GLOBAL source chunk, LDS dest stays linear.
// Staging ledger: IDENTICAL to round-2 kernel (verified):
//   p1 A(1,1,k+1)  p2 B(1,1,k+1)  p3 A(0,0,k+2)  p4 B(0,0,k+2)
//   p5 A(0,1,k+2)  p6 B(0,1,k+2)  p7 A(1,0,k+3)  p8 B(1,0,k+3)
// vmcnt(8) after even-phase stage; prologue 12 loads + vmcnt(8); drain 8/4/0.
//
// Compute: v_mfma_f32_32x32x16_bf16.  Wave output 128x64 = 4 m-tiles x
// 2 n-tiles of 32x32.  Fragment: lane row = lane&31, k = (lane>>5)*8 + j;
// 16B frag at [row][kstep*16 + hi*8] -> logical chunk = kstep*2 + hi.
// C/D: col = lane&31, row = (reg&3) + 8*(reg>>2) + 4*(lane>>5)  [m74/m101].
// One 32x32 m-tile == one class (32 proxies): epilogue = per-thread fmax
// over 16 regs + shfl_xor(32) + store (lanes 0..31).
// ---------------------------------------------------------------------------
#define WAITV(N) asm volatile("s_waitcnt vmcnt(" #N ")" ::: "memory")
#define SBAR     asm volatile("s_barrier" ::: "memory")
#define NOPS     do {} while (0)

#define STAGE_A(BUF,H,KOFF) do { \
  async_ld16(gA + (KOFF)*64 + (H)*32,         smem + (BUF)*32768 + (H)*16384 + sdst); \
  async_ld16(gA + 65536 + (KOFF)*64 + (H)*32, smem + (BUF)*32768 + (H)*16384 + sdst + 8192); \
} while(0)

#define STAGE_B(BUF,H,KOFF) do { \
  async_ld16(gB + (KOFF)*64 + (H)*32,         smem + 65536 + (BUF)*32768 + (H)*16384 + sdst); \
  async_ld16(gB + 65536 + (KOFF)*64 + (H)*32, smem + 65536 + (BUF)*32768 + (H)*16384 + sdst + 8192); \
} while(0)

// Phase: read A frags (2 m-tiles x 2 ksteps), B frags on RB phases
// (2 n-tiles x 2 ksteps), stage, wait, barrier, 8 MFMA, barrier.
#define PH(BUF,H,MH,RB, STAGE, WAIT) do { \
  if (RB) { \
    bfr00 = *(const bf16x8*)(pb0 + (BUF)*32768 + (H)*16384 + 0*2048); \
    bfr01 = *(const bf16x8*)(pb1 + (BUF)*32768 + (H)*16384 + 0*2048); \
    bfr10 = *(const bf16x8*)(pb0 + (BUF)*32768 + (H)*16384 + 1*2048); \
    bfr11 = *(const bf16x8*)(pb1 + (BUF)*32768 + (H)*16384 + 1*2048); \
  } \
  afr00 = *(const bf16x8*)(pa0 + (BUF)*32768 + (H)*16384 + ((MH)*2+0)*2048); \
  afr01 = *(const bf16x8*)(pa1 + (BUF)*32768 + (H)*16384 + ((MH)*2+0)*2048); \
  afr10 = *(const bf16x8*)(pa0 + (BUF)*32768 + (H)*16384 + ((MH)*2+1)*2048); \
  afr11 = *(const bf16x8*)(pa1 + (BUF)*32768 + (H)*16384 + ((MH)*2+1)*2048); \
  STAGE; \
  WAIT; \
  SBAR; \
  asm volatile("s_waitcnt lgkmcnt(0)" ::: "memory"); \
  __builtin_amdgcn_sched_barrier(0); \
  __builtin_amdgcn_s_setprio(1); \
  acc[(MH)*2+0][0] = __builtin_amdgcn_mfma_f32_32x32x16_bf16(afr00, bfr00, acc[(MH)*2+0][0], 0, 0, 0); \
  acc[(MH)*2+0][1] = __builtin_amdgcn_mfma_f32_32x32x16_bf16(afr00, bfr10, acc[(MH)*2+0][1], 0, 0, 0); \
  acc[(MH)*2+1][0] = __builtin_amdgcn_mfma_f32_32x32x16_bf16(afr10, bfr00, acc[(MH)*2+1][0], 0, 0, 0); \
  acc[(MH)*2+1][1] = __builtin_amdgcn_mfma_f32_32x32x16_bf16(afr10, bfr10, acc[(MH)*2+1][1], 0, 0, 0); \
  acc[(MH)*2+0][0] = __builtin_amdgcn_mfma_f32_32x32x16_bf16(afr01, bfr01, acc[(MH)*2+0][0], 0, 0, 0); \
  acc[(MH)*2+0][1] = __builtin_amdgcn_mfma_f32_32x32x16_bf16(afr01, bfr11, acc[(MH)*2+0][1], 0, 0, 0); \
  acc[(MH)*2+1][0] = __builtin_amdgcn_mfma_f32_32x32x16_bf16(afr11, bfr01, acc[(MH)*2+1][0], 0, 0, 0); \
  acc[(MH)*2+1][1] = __builtin_amdgcn_mfma_f32_32x32x16_bf16(afr11, bfr11, acc[(MH)*2+1][1], 0, 0, 0); \
  __builtin_amdgcn_s_setprio(0); \
  SBAR; \
} while(0)

__global__ __launch_bounds__(512, 2) void gemm_max_kernel(
    const unsigned short* __restrict__ wbf,   // [64000][512] bf16, normalized
    const unsigned short* __restrict__ dbf,   // [4096][512]  bf16, normalized
    float* __restrict__ out)                  // [2000][4096]
{
  extern __shared__ char smem[];              // 131072 B

  const int tid  = threadIdx.x;
  const int lane = tid & 63;
  const int wid  = tid >> 6;      // 0..7
  const int wr   = wid >> 2;      // 0..1  (128 rows each)
  const int wc   = wid & 3;       // 0..3  (64 cols each)

  // XCD-aware swizzle: 4000 blocks, 8 XCDs, 500/chunk (bijective).
  const int bid  = blockIdx.x;
  const int wgid = (bid & 7) * 500 + (bid >> 3);
  const int rowb = wgid >> 4;     // 0..249
  const int colb = wgid & 15;     // 0..15
  const int rowBase = rowb * BM;
  const int colBase = colb * BN;

  // Staging: region = 256 rows x 32 shorts = 1024 x 16B chunks; thread t
  // handles chunks t (rows 0-127) and t+512 (rows 128-255).
  const int srow = tid >> 2;
  const int gch  = (tid & 3) ^ ((tid >> 3) & 3);   // pre-swizzled global chunk
  const unsigned short* gA = wbf + (size_t)(rowBase + srow) * E_DIM + gch * 8;
  const unsigned short* gB = dbf + (size_t)(colBase + srow) * E_DIM + gch * 8;
  const int sdst = tid * 16;      // linear LDS dest

  // Fragment read bases.  row32 = lane&31, hi = lane>>5;
  // logical chunk for kstep ks = ks*2 + hi; stored slot = logical ^ f(row).
  const int r32 = lane & 31;
  const int hi  = lane >> 5;
  const int f   = (r32 >> 1) & 3;
  const int c0  = (hi ^ f) * 16;          // kstep 0 chunk byte offset
  const int c1  = ((2 + hi) ^ f) * 16;    // kstep 1
  const char* pa0 = smem + (wr * 128 + r32) * 64 + c0;
  const char* pa1 = smem + (wr * 128 + r32) * 64 + c1;
  const char* pb0 = smem + 65536 + (wc * 64 + r32) * 64 + c0;
  const char* pb1 = smem + 65536 + (wc * 64 + r32) * 64 + c1;

  f32x16 acc[4][2];
  #pragma unroll
  for (int m = 0; m < 4; ++m)
    #pragma unroll
    for (int n = 0; n < 2; ++n)
      acc[m][n] = (f32x16)0.f;
  bf16x8 afr00, afr01, afr10, afr11, bfr00, bfr01, bfr10, bfr11;

  // Prologue: 12 loads (regions 0.h0, 0.h1, 1.h0), oldest 4 needed first.
  STAGE_A(0,0,0); STAGE_B(0,0,0);
  STAGE_A(0,1,0); STAGE_B(0,1,0);
  STAGE_A(1,0,1); STAGE_B(1,0,1);
  WAITV(8);
  SBAR;

  #pragma unroll 1
  for (int kt = 0; kt < 6; kt += 2) {
    PH(0,0,0,1, STAGE_A(1,1,kt+1), NOPS);
    PH(0,0,1,0, STAGE_B(1,1,kt+1), WAITV(8));
    PH(0,1,0,1, STAGE_A(0,0,kt+2), NOPS);
    PH(0,1,1,0, STAGE_B(0,0,kt+2), WAITV(8));
    PH(1,0,0,1, STAGE_A(0,1,kt+2), NOPS);
    PH(1,0,1,0, STAGE_B(0,1,kt+2), WAITV(8));
    PH(1,1,0,1, STAGE_A(1,0,kt+3), NOPS);
    PH(1,1,1,0, STAGE_B(1,0,kt+3), WAITV(8));
  }
  // Drain iteration (kt=6): only tile7.h1 left to stage.
  PH(0,0,0,1, STAGE_A(1,1,7), NOPS);
  PH(0,0,1,0, STAGE_B(1,1,7), WAITV(8));
  PH(0,1,0,1, NOPS,           NOPS);
  PH(0,1,1,0, NOPS,           WAITV(4));
  PH(1,0,0,1, NOPS,           NOPS);
  PH(1,0,1,0, NOPS,           WAITV(0));
  PH(1,1,0,1, NOPS,           NOPS);
  PH(1,1,1,0, NOPS,           NOPS);

  // Epilogue: one 32x32 m-tile == one class.  C/D: col = lane&31,
  // row = (reg&3) + 8*(reg>>2) + 4*hi.  fmax over 16 regs + shfl_xor(32).
  float* outp = out + (size_t)(rowb * 8 + wr * 4) * B_Q +
                colBase + wc * 64 + r32;
  #pragma unroll
  for (int m = 0; m < 4; ++m) {
    #pragma unroll
    for (int n = 0; n < 2; ++n) {
      float pm = acc[m][n][0];
      #pragma unroll
      for (int j = 1; j < 16; ++j) pm = fmaxf(pm, acc[m][n][j]);
      pm = fmaxf(pm, __shfl_xor(pm, 32));
      if (lane < 32) outp[(size_t)m * B_Q + n * 32] = pm;
    }
  }
}

// ---------------------------------------------------------------------------
extern "C" void kernel_launch(void* const* d_in, const int* in_sizes, int n_in,
                              void* d_out, int out_size, void* d_ws, size_t ws_size,
                              hipStream_t stream) {
  const float* data = (const float*)d_in[0];   // [4096][512]
  const float* w1   = (const float*)d_in[1];   // [64000][512]
  float* out = (float*)d_out;                  // [2000][4096]

  unsigned short* wbf = (unsigned short*)d_ws;
  unsigned short* dbf = wbf + (size_t)N_P * E_DIM;

  (void)hipFuncSetAttribute((const void*)gemm_max_kernel,
      hipFuncAttributeMaxDynamicSharedMemorySize, 131072);

  norm_rows_kernel<<<N_P + B_Q, 128, 0, stream>>>(w1, data, wbf, dbf);
  gemm_max_kernel<<<4000, 512, 131072, stream>>>(wbf, dbf, out);
}

// Round 7
// 285.234 us; speedup vs baseline: 1.3270x; 1.0287x over previous
//
#include <hip/hip_runtime.h>

// Problem constants
#define B_Q   4096
#define E_DIM 512
#define N_C   2000
#define N_P   64000

// GEMM geometry: 256x256 tile, BK=64 (2 K-halves of 32), 8 waves (2M x 4N),
// 8-phase schedule, double-buffered 128 KiB LDS, 16x16x32 MFMA.
// NEW vs round 2: fragment ds_reads are software-pipelined one phase ahead
// (issued at the TAIL of the previous phase, into the alternate register
// set), so the LDS read burst overlaps the MFMA pipe instead of serializing
// before it.
#define BM 256
#define BN 256

typedef __bf16 bf16x8 __attribute__((ext_vector_type(8)));
typedef float  f32x4  __attribute__((ext_vector_type(4)));

__device__ __forceinline__ unsigned short f2bf(float f) {
  unsigned u = __builtin_bit_cast(unsigned, f);
  u += 0x7fffu + ((u >> 16) & 1u);
  return (unsigned short)(u >> 16);
}

__device__ __forceinline__ void async_ld16(const void* g, void* l) {
  __builtin_amdgcn_global_load_lds(
      (const __attribute__((address_space(1))) void*)g,
      (__attribute__((address_space(3))) void*)l,
      16, 0, 0);
}

// ---------------------------------------------------------------------------
// Row L2-normalize fp32 -> bf16 for BOTH inputs in one launch.
// ---------------------------------------------------------------------------
__global__ __launch_bounds__(128) void norm_rows_kernel(
    const float* __restrict__ w1, const float* __restrict__ data,
    unsigned short* __restrict__ wbf, unsigned short* __restrict__ dbf)
{
  int row = blockIdx.x;
  const float* in;
  unsigned short* outbf;
  if (row < N_P) { in = w1; outbf = wbf; }
  else           { in = data; outbf = dbf; row -= N_P; }
  const int tid = threadIdx.x;
  const float4 v = *(const float4*)(in + (size_t)row * E_DIM + tid * 4);
  float ss = v.x*v.x + v.y*v.y + v.z*v.z + v.w*v.w;
  #pragma unroll
  for (int s = 1; s < 64; s <<= 1) ss += __shfl_xor(ss, s);
  __shared__ float partial[2];
  if ((tid & 63) == 0) partial[tid >> 6] = ss;
  __syncthreads();
  const float tot = partial[0] + partial[1];
  const float inv = 1.0f / fmaxf(sqrtf(tot), 1e-12f);
  ushort4 o;
  o.x = f2bf(v.x * inv); o.y = f2bf(v.y * inv);
  o.z = f2bf(v.z * inv); o.w = f2bf(v.w * inv);
  *(ushort4*)(outbf + (size_t)row * E_DIM + tid * 4) = o;
}

// ---------------------------------------------------------------------------
// LDS: A[buf][h][256 rows][4 x 16B] @0, B same @65536; region = 16 KiB.
// Chunk swizzle: slot (row,cc) holds global chunk cc ^ ((row>>1)&3); stager
// pre-swizzles the GLOBAL source chunk, LDS dest stays linear.
// Staging ledger (verified round 2): per ii-block (k-tile k on buf0 ph1-4,
// k+1 on buf1 ph5-8):
//   p1 A(1,1,k+1)  p2 B(1,1,k+1)  p3 A(0,0,k+2)  p4 B(0,0,k+2)
//   p5 A(0,1,k+2)  p6 B(0,1,k+2)  p7 A(1,0,k+3)  p8 B(1,0,k+3)
// WAITV(8) after even-phase stage guarantees regions staged >=4 phases back
// have landed.  Tail-read coverage (reads of phase p+1 issued at end of p):
//   p1 tail (0,0)  staged prev p3/p4  -> landed by prev-p8 WAITV(8)
//   p2 tail (0,1)  staged prev p5/p6  -> landed by p2 WAITV(8)
//   p4 tail (1,0)  staged prev p7/p8  -> landed by p4 WAITV(8)
//   p6 tail (1,1)  staged cur  p1/p2  -> landed by p6 WAITV(8)
//   p8 tail (0,0)  staged cur  p3/p4  -> landed by p8 WAITV(8)
// LDS WAR: every phase drains lgkm before MFMA + trailing barrier, so a
// region's reads complete >=1 phase before it is restaged (>=2 phase gap).
// ---------------------------------------------------------------------------
#define WAITV(N) asm volatile("s_waitcnt vmcnt(" #N ")" ::: "memory")
#define SBAR     asm volatile("s_barrier" ::: "memory")
#define NOPS     do {} while (0)

#define STAGE_A(BUF,H,KOFF) do { \
  async_ld16(gA + (KOFF)*64 + (H)*32,         smem + (BUF)*32768 + (H)*16384 + sdst); \
  async_ld16(gA + 65536 + (KOFF)*64 + (H)*32, smem + (BUF)*32768 + (H)*16384 + sdst + 8192); \
} while(0)

#define STAGE_B(BUF,H,KOFF) do { \
  async_ld16(gB + (KOFF)*64 + (H)*32,         smem + 65536 + (BUF)*32768 + (H)*16384 + sdst); \
  async_ld16(gB + 65536 + (KOFF)*64 + (H)*32, smem + 65536 + (BUF)*32768 + (H)*16384 + sdst + 8192); \
} while(0)

// Fragment-register double buffering: A sets alternate every phase,
// B sets alternate every 2 phases (B frags serve an MH0/MH1 phase pair).
#define RDA(S,BUF,H,MH) do { \
  a##S##_0 = *(const bf16x8*)(pa + (BUF)*32768 + (H)*16384 + ((MH)*4+0)*1024); \
  a##S##_1 = *(const bf16x8*)(pa + (BUF)*32768 + (H)*16384 + ((MH)*4+1)*1024); \
  a##S##_2 = *(const bf16x8*)(pa + (BUF)*32768 + (H)*16384 + ((MH)*4+2)*1024); \
  a##S##_3 = *(const bf16x8*)(pa + (BUF)*32768 + (H)*16384 + ((MH)*4+3)*1024); \
} while(0)

#define RDB(S,BUF,H) do { \
  b##S##_0 = *(const bf16x8*)(pb + (BUF)*32768 + (H)*16384 +    0); \
  b##S##_1 = *(const bf16x8*)(pb + (BUF)*32768 + (H)*16384 + 1024); \
  b##S##_2 = *(const bf16x8*)(pb + (BUF)*32768 + (H)*16384 + 2048); \
  b##S##_3 = *(const bf16x8*)(pb + (BUF)*32768 + (H)*16384 + 3072); \
} while(0)

#define MM(AS,BS,MH,m,n) \
  acc[(MH)*4+m][n] = __builtin_amdgcn_mfma_f32_16x16x32_bf16( \
      a##AS##_##m, b##BS##_##n, acc[(MH)*4+m][n], 0, 0, 0)

#define MFMA16(AS,BS,MH) do { \
  MM(AS,BS,MH,0,0); MM(AS,BS,MH,0,1); MM(AS,BS,MH,0,2); MM(AS,BS,MH,0,3); \
  MM(AS,BS,MH,1,0); MM(AS,BS,MH,1,1); MM(AS,BS,MH,1,2); MM(AS,BS,MH,1,3); \
  MM(AS,BS,MH,2,0); MM(AS,BS,MH,2,1); MM(AS,BS,MH,2,2); MM(AS,BS,MH,2,3); \
  MM(AS,BS,MH,3,0); MM(AS,BS,MH,3,1); MM(AS,BS,MH,3,2); MM(AS,BS,MH,3,3); \
} while(0)

// Phase: stage, vmcnt wait, barrier, lgkm drain (covers last phase's tail
// reads), MFMA on current frag sets, tail-read next phase's frags, barrier.
#define PHX(AS,BS,MH, STAGE, WAIT, TAIL) do { \
  STAGE; \
  WAIT; \
  SBAR; \
  asm volatile("s_waitcnt lgkmcnt(0)" ::: "memory"); \
  __builtin_amdgcn_sched_barrier(0); \
  __builtin_amdgcn_s_setprio(1); \
  MFMA16(AS,BS,MH); \
  __builtin_amdgcn_s_setprio(0); \
  TAIL; \
  SBAR; \
} while(0)

// ii-block: phases (buf,h,MH) = (0,0,0)(0,0,1)(0,1,0)(0,1,1)(1,0,0)(1,0,1)
// (1,1,0)(1,1,1); A-set = phase parity, B-set toggles each even-phase tail.
#define IIBLK(K1,K2,K3) do { \
  PHX(0,0,0, STAGE_A(1,1,K1), NOPS,     RDA(1,0,0,1)); \
  PHX(1,0,1, STAGE_B(1,1,K1), WAITV(8), RDA(0,0,1,0); RDB(1,0,1)); \
  PHX(0,1,0, STAGE_A(0,0,K2), NOPS,     RDA(1,0,1,1)); \
  PHX(1,1,1, STAGE_B(0,0,K2), WAITV(8), RDA(0,1,0,0); RDB(0,1,0)); \
  PHX(0,0,0, STAGE_A(0,1,K2), NOPS,     RDA(1,1,0,1)); \
  PHX(1,0,1, STAGE_B(0,1,K2), WAITV(8), RDA(0,1,1,0); RDB(1,1,1)); \
  PHX(0,1,0, STAGE_A(1,0,K3), NOPS,     RDA(1,1,1,1)); \
  PHX(1,1,1, STAGE_B(1,0,K3), WAITV(8), RDA(0,0,0,0); RDB(0,0,0)); \
} while(0)

__global__ __launch_bounds__(512, 2) void gemm_max_kernel(
    const unsigned short* __restrict__ wbf,   // [64000][512] bf16, normalized
    const unsigned short* __restrict__ dbf,   // [4096][512]  bf16, normalized
    float* __restrict__ out)                  // [2000][4096]
{
  extern __shared__ char smem[];              // 131072 B

  const int tid  = threadIdx.x;
  const int lane = tid & 63;
  const int wid  = tid >> 6;      // 0..7
  const int wr   = wid >> 2;      // 0..1  (128 rows each)
  const int wc   = wid & 3;       // 0..3  (64 cols each)

  // XCD-aware swizzle: 4000 blocks, 8 XCDs, 500/chunk (bijective).
  const int bid  = blockIdx.x;
  const int wgid = (bid & 7) * 500 + (bid >> 3);
  const int rowb = wgid >> 4;     // 0..249
  const int colb = wgid & 15;     // 0..15
  const int rowBase = rowb * BM;
  const int colBase = colb * BN;

  // Staging: region = 256 rows x 32 shorts = 1024 x 16B chunks; thread t
  // handles chunks t (rows 0-127) and t+512 (rows 128-255).
  const int srow = tid >> 2;
  const int gch  = (tid & 3) ^ ((tid >> 3) & 3);   // pre-swizzled global chunk
  const unsigned short* gA = wbf + (size_t)(rowBase + srow) * E_DIM + gch * 8;
  const unsigned short* gB = dbf + (size_t)(colBase + srow) * E_DIM + gch * 8;
  const int sdst = tid * 16;      // linear LDS dest

  // Fragment read bases (swizzled chunk) -- identical to round 2 (0 conflicts)
  const int r   = lane & 15;
  const int kg  = lane >> 4;
  const int swz = (kg ^ ((r >> 1) & 3)) * 16;
  const char* pa = smem + (wr * 128 + r) * 64 + swz;
  const char* pb = smem + 65536 + (wc * 64 + r) * 64 + swz;

  f32x4 acc[8][4];
  #pragma unroll
  for (int m = 0; m < 8; ++m)
    #pragma unroll
    for (int n = 0; n < 4; ++n)
      acc[m][n] = (f32x4){0.f, 0.f, 0.f, 0.f};

  bf16x8 a0_0, a0_1, a0_2, a0_3, a1_0, a1_1, a1_2, a1_3;
  bf16x8 b0_0, b0_1, b0_2, b0_3, b1_0, b1_1, b1_2, b1_3;

  // Prologue: 12 loads (regions 0.h0, 0.h1, 1.h0), oldest 4 needed first;
  // then pre-read phase-1's fragments into set 0.
  STAGE_A(0,0,0); STAGE_B(0,0,0);
  STAGE_A(0,1,0); STAGE_B(0,1,0);
  STAGE_A(1,0,1); STAGE_B(1,0,1);
  WAITV(8);
  SBAR;
  RDA(0,0,0,0);
  RDB(0,0,0);

  #pragma unroll 1
  for (int kt = 0; kt < 6; kt += 2) {
    IIBLK(kt+1, kt+2, kt+3);
  }
  // Drain ii-block (kt=6): only tile7.h1 left to stage; waits 8/4/0.
  PHX(0,0,0, STAGE_A(1,1,7), NOPS,     RDA(1,0,0,1));
  PHX(1,0,1, STAGE_B(1,1,7), WAITV(8), RDA(0,0,1,0); RDB(1,0,1));
  PHX(0,1,0, NOPS,           NOPS,     RDA(1,0,1,1));
  PHX(1,1,1, NOPS,           WAITV(4), RDA(0,1,0,0); RDB(0,1,0));
  PHX(0,0,0, NOPS,           NOPS,     RDA(1,1,0,1));
  PHX(1,0,1, NOPS,           WAITV(0), RDA(0,1,1,0); RDB(1,1,1));
  PHX(0,1,0, NOPS,           NOPS,     RDA(1,1,1,1));
  PHX(1,1,1, NOPS,           NOPS,     NOPS);

  // Epilogue: per-class max (class = 32 rows = m-pair).  Wave row =
  // wr*128 + m*16 + kg*4 + j; reduce m-pair x j, then across kg (lanes).
  const int classBase = rowb * 8 + wr * 4;
  #pragma unroll
  for (int q = 0; q < 4; ++q) {
    #pragma unroll
    for (int n = 0; n < 4; ++n) {
      float pm = -3.4e38f;
      #pragma unroll
      for (int j = 0; j < 4; ++j)
        pm = fmaxf(pm, fmaxf(acc[2*q][n][j], acc[2*q+1][n][j]));
      pm = fmaxf(pm, __shfl_xor(pm, 16));
      pm = fmaxf(pm, __shfl_xor(pm, 32));
      if (lane < 16)
        out[(size_t)(classBase + q) * B_Q + colBase + wc * 64 + n * 16 + r] = pm;
    }
  }
}

// ---------------------------------------------------------------------------
extern "C" void kernel_launch(void* const* d_in, const int* in_sizes, int n_in,
                              void* d_out, int out_size, void* d_ws, size_t ws_size,
                              hipStream_t stream) {
  const float* data = (const float*)d_in[0];   // [4096][512]
  const float* w1   = (const float*)d_in[1];   // [64000][512]
  float* out = (float*)d_out;                  // [2000][4096]

  unsigned short* wbf = (unsigned short*)d_ws;
  unsigned short* dbf = wbf + (size_t)N_P * E_DIM;

  (void)hipFuncSetAttribute((const void*)gemm_max_kernel,
      hipFuncAttributeMaxDynamicSharedMemorySize, 131072);

  norm_rows_kernel<<<N_P + B_Q, 128, 0, stream>>>(w1, data, wbf, dbf);
  gemm_max_kernel<<<4000, 512, 131072, stream>>>(wbf, dbf, out);
}